// Round 3
// baseline (52.956 us; speedup 1.0000x reference)
//
#include <hip/hip_runtime.h>
#include <hip/hip_bf16.h>

#define N_PTS 128
#define FAR_DELTA 1e10f
#define EPS 1e-10f

// ---------------------------------------------------------------------------
// Kernel 1: global max of depth_values. Rows are sorted ascending (per
// setup_inputs), so the global max is the max over the last column.
// atomicMax on float bits is order-preserving for positive floats; d_ws is
// zeroed before this kernel each call.
// ---------------------------------------------------------------------------
__global__ __launch_bounds__(256) void vr_depth_max(
    const float* __restrict__ depth, float* __restrict__ gmax, int n_rays)
{
    int i = blockIdx.x * blockDim.x + threadIdx.x;
    float v = 0.0f;
    if (i < n_rays) v = depth[(size_t)i * N_PTS + (N_PTS - 1)];
    // wave-64 max reduce
    #pragma unroll
    for (int off = 32; off > 0; off >>= 1)
        v = fmaxf(v, __shfl_xor(v, off, 64));
    if ((threadIdx.x & 63) == 0)
        atomicMax((int*)gmax, __float_as_int(v));
}

// ---------------------------------------------------------------------------
// Kernel 2: fused volume rendering. One 64-lane wave per ray; lane l owns
// sample points l and l+64. Exclusive cumsum of s = rho*(delta+eps) via
// wave-wide inclusive shfl_up scan.
//
// NOTE: s at the global last sample (lane 63, B half) is ~rho*1e10. It must
// NOT enter the scan: "inclusive - own" would cancel catastrophically (ulp of
// 2e10 is ~2048 -> expf(+garbage) = inf). The reference's exclusive shift
// drops that element entirely, so we zero it before scanning.
// ---------------------------------------------------------------------------
__device__ __forceinline__ float wave_incl_scan(float v, int lane)
{
    #pragma unroll
    for (int off = 1; off < 64; off <<= 1) {
        float n = __shfl_up(v, off, 64);
        if (lane >= off) v += n;
    }
    return v;
}

__global__ __launch_bounds__(256) void vr_main(
    const float* __restrict__ depth,    // [n_rays, 128]
    const float* __restrict__ density,  // [n_rays, 128, 1]
    const float* __restrict__ feature,  // [n_rays, 128, 3]
    const float* __restrict__ gmax_ptr, // [1]
    float* __restrict__ feat_out,       // [n_rays, 3]
    float* __restrict__ depth_out,      // [n_rays, 1]
    int n_rays)
{
    const int gtid = blockIdx.x * blockDim.x + threadIdx.x;
    const int ray  = gtid >> 6;
    const int lane = threadIdx.x & 63;
    if (ray >= n_rays) return;

    const float inv_gmax = 1.0f / gmax_ptr[0];

    const float* dp = depth   + (size_t)ray * N_PTS;
    const float* rp = density + (size_t)ray * N_PTS;
    const float* fp = feature + (size_t)ray * N_PTS * 3;

    // ---- loads (coalesced) ----
    float dA = dp[lane];        // depth of point p = lane
    float dB = dp[lane + 64];   // depth of point p = lane + 64
    float rA = rp[lane];
    float rB = rp[lane + 64];

    // ---- deltas via shuffles ----
    float nA      = __shfl(dA, (lane + 1) & 63, 64);
    float firstB  = __shfl(dB, 0, 64);
    float deltaA  = ((lane == 63) ? firstB : nA) - dA;
    float nB      = __shfl(dB, (lane + 1) & 63, 64);
    float deltaB  = (lane == 63) ? FAR_DELTA : (nB - dB);

    // ---- s = rho * (delta + eps); exclusive cumsum over 128 points ----
    float sA = rA * (deltaA + EPS);
    float sB = rB * (deltaB + EPS);

    // zero the (huge) last element for the scan: no exclusive prefix uses it
    float sBs = (lane == 63) ? 0.0f : sB;

    float incA   = wave_incl_scan(sA, lane);
    float totalA = __shfl(incA, 63, 64);
    float incB   = wave_incl_scan(sBs, lane);

    float exclA = incA - sA;             // sum of s[0..p-1], p = lane
    float exclB = totalA + incB - sBs;   // p = lane + 64

    // ---- weights: trans * (1 - exp(-rho*delta + eps)) ----
    float transA = expf(-exclA);
    float transB = expf(-exclB);
    float wA = transA * (1.0f - expf(fmaf(-rA, deltaA, EPS)));
    float wB = transB * (1.0f - expf(fmaf(-rB, deltaB, EPS)));

    // ---- feature loads: 3 consecutive floats per lane (contiguous wave) ----
    const float* fa = fp + lane * 3;
    const float* fb = fp + (lane + 64) * 3;
    float acc0 = wA * fa[0] + wB * fb[0];
    float acc1 = wA * fa[1] + wB * fb[1];
    float acc2 = wA * fa[2] + wB * fb[2];
    float accd = (wA * dA + wB * dB) * inv_gmax;

    // ---- wave-64 sum reduce (4 values) ----
    #pragma unroll
    for (int off = 32; off > 0; off >>= 1) {
        acc0 += __shfl_xor(acc0, off, 64);
        acc1 += __shfl_xor(acc1, off, 64);
        acc2 += __shfl_xor(acc2, off, 64);
        accd += __shfl_xor(accd, off, 64);
    }

    if (lane == 0) {
        float* fo = feat_out + (size_t)ray * 3;
        fo[0] = acc0;
        fo[1] = acc1;
        fo[2] = acc2;
        depth_out[ray] = accd;
    }
}

extern "C" void kernel_launch(void* const* d_in, const int* in_sizes, int n_in,
                              void* d_out, int out_size, void* d_ws, size_t ws_size,
                              hipStream_t stream)
{
    const float* depth   = (const float*)d_in[0];
    const float* density = (const float*)d_in[1];
    const float* feature = (const float*)d_in[2];

    const int n_rays = in_sizes[0] / N_PTS;

    float* out       = (float*)d_out;
    float* feat_out  = out;                        // [n_rays, 3]
    float* depth_out = out + (size_t)n_rays * 3;   // [n_rays, 1]
    float* gmax      = (float*)d_ws;

    // zero the atomicMax cell (workspace is NOT re-poisoned between replays,
    // but it IS poisoned to 0xAA once -> must init every call)
    (void)hipMemsetAsync(d_ws, 0, sizeof(float), stream);

    {
        int threads = 256;
        int blocks  = (n_rays + threads - 1) / threads;
        vr_depth_max<<<blocks, threads, 0, stream>>>(depth, gmax, n_rays);
    }
    {
        // one wave (64 lanes) per ray, 4 rays per 256-thread block
        int threads = 256;
        int blocks  = (n_rays * 64 + threads - 1) / threads;
        vr_main<<<blocks, threads, 0, stream>>>(depth, density, feature, gmax,
                                                feat_out, depth_out, n_rays);
    }
}

// Round 4
// 47.466 us; speedup vs baseline: 1.1157x; 1.1157x over previous
//
#include <hip/hip_runtime.h>

#define N_PTS 128
#define FAR_DELTA 1e10f
#define EPS 1e-10f

// ---------------------------------------------------------------------------
// Kernel 1: global max of depth_values. Rows are sorted ascending (per
// setup_inputs), so the global max is the max over the last column.
// atomicMax on float bits is order-preserving for positive floats; d_ws is
// zeroed before this kernel each call (cheap 4B memset — initial ws content
// before the first correctness call is unknown).
// ---------------------------------------------------------------------------
__global__ __launch_bounds__(256) void vr_depth_max(
    const float* __restrict__ depth, float* __restrict__ gmax, int n_rays)
{
    int i = blockIdx.x * blockDim.x + threadIdx.x;
    float v = 0.0f;
    if (i < n_rays) v = depth[(size_t)i * N_PTS + (N_PTS - 1)];
    #pragma unroll
    for (int off = 32; off > 0; off >>= 1)
        v = fmaxf(v, __shfl_xor(v, off, 64));
    if ((threadIdx.x & 63) == 0)
        atomicMax((int*)gmax, __float_as_int(v));
}

// ---------------------------------------------------------------------------
// Kernel 2: fused volume rendering. 32 lanes per ray (2 rays per wave64),
// lane sl owns points 4sl..4sl+3. All global loads are dwordx4.
//
// Exclusive cumsum of s = rho*(delta+eps): 3-add local prefix + 5-step
// segmented shfl_up scan over per-lane totals (width=32 partitions wave64
// into per-ray halves).
//
// s at the global last point (sl==31, elem 3) is ~rho*1e10 and must NOT
// enter the scan totals ("inclusive - own" would cancel catastrophically);
// the reference's exclusive shift drops that element entirely, so we zero
// it in the total. No exclusive prefix ever contains it.
// ---------------------------------------------------------------------------
__global__ __launch_bounds__(256) void vr_main(
    const float* __restrict__ depth,    // [n_rays, 128]
    const float* __restrict__ density,  // [n_rays, 128, 1]
    const float* __restrict__ feature,  // [n_rays, 128, 3]
    const float* __restrict__ gmax_ptr, // [1]
    float* __restrict__ feat_out,       // [n_rays, 3]
    float* __restrict__ depth_out,      // [n_rays, 1]
    int n_rays)
{
    const int tid  = blockIdx.x * blockDim.x + threadIdx.x;
    const int ray  = tid >> 5;          // 32 lanes per ray
    const int sl   = threadIdx.x & 31;  // lane within ray segment
    if (ray >= n_rays) return;

    const float inv_gmax = 1.0f / gmax_ptr[0];

    // ---- vectorized loads: lane sl owns points 4sl..4sl+3 ----
    const float4* dp4 = (const float4*)(depth   + (size_t)ray * N_PTS);
    const float4* rp4 = (const float4*)(density + (size_t)ray * N_PTS);
    const float4* fp4 = (const float4*)(feature + (size_t)ray * N_PTS * 3);

    float4 d4 = dp4[sl];
    float4 r4 = rp4[sl];
    float4 f0 = fp4[sl * 3 + 0];   // {p0.r p0.g p0.b p1.r}
    float4 f1 = fp4[sl * 3 + 1];   // {p1.g p1.b p2.r p2.g}
    float4 f2 = fp4[sl * 3 + 2];   // {p2.b p3.r p3.g p3.b}

    // ---- deltas ----
    float nd = __shfl_down(d4.x, 1, 32);   // next lane's first depth
    float delta0 = d4.y - d4.x;
    float delta1 = d4.z - d4.y;
    float delta2 = d4.w - d4.z;
    float delta3 = (sl == 31) ? FAR_DELTA : (nd - d4.w);

    // ---- s = rho*(delta+eps), local prefix, segmented scan of totals ----
    float s0 = r4.x * (delta0 + EPS);
    float s1 = r4.y * (delta1 + EPS);
    float s2 = r4.z * (delta2 + EPS);
    float s3 = r4.w * (delta3 + EPS);

    float p1 = s0;
    float p2 = s0 + s1;
    float p3 = p2 + s2;
    float t  = p3 + ((sl == 31) ? 0.0f : s3);  // drop the huge last element

    float inc = t;
    #pragma unroll
    for (int off = 1; off < 32; off <<= 1) {
        float n = __shfl_up(inc, off, 32);
        if (sl >= off) inc += n;
    }
    float excl = inc - t;   // sum of totals of lanes 0..sl-1 (all benign)

    // ---- weights: trans * (1 - exp(-rho*delta + eps)) ----
    float w0 = __expf(-excl)        * (1.0f - __expf(fmaf(-r4.x, delta0, EPS)));
    float w1 = __expf(-(excl + p1)) * (1.0f - __expf(fmaf(-r4.y, delta1, EPS)));
    float w2 = __expf(-(excl + p2)) * (1.0f - __expf(fmaf(-r4.z, delta2, EPS)));
    float w3 = __expf(-(excl + p3)) * (1.0f - __expf(fmaf(-r4.w, delta3, EPS)));

    // ---- accumulate rgb + normalized depth ----
    float acc0 = w0 * f0.x + w1 * f0.w + w2 * f1.z + w3 * f2.y;
    float acc1 = w0 * f0.y + w1 * f1.x + w2 * f1.w + w3 * f2.z;
    float acc2 = w0 * f0.z + w1 * f1.y + w2 * f2.x + w3 * f2.w;
    float accd = (w0 * d4.x + w1 * d4.y + w2 * d4.z + w3 * d4.w) * inv_gmax;

    // ---- 32-lane segmented sum reduce ----
    #pragma unroll
    for (int off = 16; off > 0; off >>= 1) {
        acc0 += __shfl_xor(acc0, off, 32);
        acc1 += __shfl_xor(acc1, off, 32);
        acc2 += __shfl_xor(acc2, off, 32);
        accd += __shfl_xor(accd, off, 32);
    }

    if (sl == 0) {
        float* fo = feat_out + (size_t)ray * 3;
        fo[0] = acc0;
        fo[1] = acc1;
        fo[2] = acc2;
        depth_out[ray] = accd;
    }
}

extern "C" void kernel_launch(void* const* d_in, const int* in_sizes, int n_in,
                              void* d_out, int out_size, void* d_ws, size_t ws_size,
                              hipStream_t stream)
{
    const float* depth   = (const float*)d_in[0];
    const float* density = (const float*)d_in[1];
    const float* feature = (const float*)d_in[2];

    const int n_rays = in_sizes[0] / N_PTS;

    float* out       = (float*)d_out;
    float* feat_out  = out;                        // [n_rays, 3]
    float* depth_out = out + (size_t)n_rays * 3;   // [n_rays, 1]
    float* gmax      = (float*)d_ws;

    (void)hipMemsetAsync(d_ws, 0, sizeof(float), stream);

    {
        int threads = 256;
        int blocks  = (n_rays + threads - 1) / threads;
        vr_depth_max<<<blocks, threads, 0, stream>>>(depth, gmax, n_rays);
    }
    {
        // 32 lanes per ray -> 8 rays per 256-thread block
        int threads = 256;
        int blocks  = (n_rays * 32 + threads - 1) / threads;
        vr_main<<<blocks, threads, 0, stream>>>(depth, density, feature, gmax,
                                                feat_out, depth_out, n_rays);
    }
}